// Round 1
// baseline (607.084 us; speedup 1.0000x reference)
//
#include <hip/hip_runtime.h>
#include <hip/hip_bf16.h>

// CrystalHypergraphConv — MI355X implementation.
//
// z[e] = A[idx0[e]] + C[idx1[e]];  A [N,256] bf16-packed; C [NHE,256]
// fp8-e4m3-packed. Lane l owns channels {2l,2l+1,128+2l,129+2l}.
//
// R17 -> R18: k_aggr/k_stats VALU compression.
//  - sidx1 now stores BYTE offsets (idx1*256); gathers become
//    SGPR-base + 32-bit voffset (saddr form): 1 v_add per gather instead
//    of a 64-bit mul+carry chain.
//  - per-edge arithmetic rewritten on f32x2 so the backend emits packed
//    v_pk_fma_f32 / v_pk_add_f32 / v_pk_mul_f32 (the fp8 HW decode already
//    yields f32x2 pairs); halves the full-rate VALU op count.
//  - BN1 stats factored: sum_z = sum(deg*a) + sum(c);
//    sumsq_z = sum(deg*a^2) + 2*sum(a*csr) + sum(c^2). The deg-weighted A
//    moments move to k_rowstats (N-row stream); k_stats' per-edge body is
//    now 2 decode + 2 pk_add + 2 pk_fma.

#define EPS_BN 1e-5f
#define LOG2E 1.4426950408889634f
#define LN2   0.6931471805599453f

typedef __attribute__((ext_vector_type(8))) short bf16x8;
typedef __attribute__((ext_vector_type(4))) float f32x4;
typedef __attribute__((ext_vector_type(2))) float f32x2;

__device__ __forceinline__ float fexp2(float x) {
#if __has_builtin(__builtin_amdgcn_exp2f)
    return __builtin_amdgcn_exp2f(x);
#else
    return __expf(x * LN2);
#endif
}
__device__ __forceinline__ float flog2(float x) {
#if __has_builtin(__builtin_amdgcn_logf)
    return __builtin_amdgcn_logf(x);
#else
    return __logf(x) * LOG2E;
#endif
}
__device__ __forceinline__ float softplus_fast(float x) {
    return LN2 * flog2(1.f + fexp2(x * LOG2E));
}

__device__ __forceinline__ f32x2 pk_fma2(f32x2 a, f32x2 b, f32x2 c) {
#if __has_builtin(__builtin_elementwise_fma)
    return __builtin_elementwise_fma(a, b, c);
#else
    return (f32x2){fmaf(a.x, b.x, c.x), fmaf(a.y, b.y, c.y)};
#endif
}

__device__ __forceinline__ unsigned short f2bf(float f) {
    unsigned u = __float_as_uint(f);
    unsigned r = (u + 0x7fffu + ((u >> 16) & 1u)) >> 16;   // RNE
    return (unsigned short)r;
}
__device__ __forceinline__ float bflo(unsigned u) { return __uint_as_float(u << 16); }
__device__ __forceinline__ float bfhi(unsigned u) { return __uint_as_float(u & 0xffff0000u); }
__device__ __forceinline__ float bfu16(unsigned short v) { return __uint_as_float(((unsigned)v) << 16); }
__device__ __forceinline__ unsigned pack2bf(float x, float y) {
    return (unsigned)f2bf(x) | ((unsigned)f2bf(y) << 16);
}

// ---- fp8 e4m3 encode/decode (OCP; HW path on gfx950) ----
#if __has_builtin(__builtin_amdgcn_cvt_pk_f32_fp8) && __has_builtin(__builtin_amdgcn_cvt_pk_fp8_f32)
#define HW_FP8 1
#else
#define HW_FP8 0
#endif

__device__ __forceinline__ unsigned char f2fp8(float f) {
#if HW_FP8
    int r = __builtin_amdgcn_cvt_pk_fp8_f32(f, f, 0, false);
    return (unsigned char)(r & 0xff);
#else
    unsigned u = __float_as_uint(f);
    unsigned s = (u >> 24) & 0x80u;
    float af = fabsf(f);
    if (!(af >= 0.015625f)) {
        int m = (int)rintf(af * 512.f);
        if (m > 7) m = 7;
        return (unsigned char)(s | (unsigned)m);
    }
    if (af > 448.f) return (unsigned char)(s | 0x7e);
    unsigned au = __float_as_uint(af);
    unsigned r = au + 0x7ffffu + ((au >> 20) & 1u);
    int e8 = (int)(r >> 23) - 120;
    unsigned m = (r >> 20) & 7u;
    if (e8 > 15 || (e8 == 15 && m == 7)) return (unsigned char)(s | 0x7e);
    return (unsigned char)(s | ((unsigned)e8 << 3) | m);
#endif
}

// decode packed word -> lo pair (bytes 0,1 = f channels), hi pair (bytes 2,3 = c channels)
__device__ __forceinline__ void fp8pair(unsigned p, f32x2& lo, f32x2& hi) {
#if HW_FP8
    lo = __builtin_amdgcn_cvt_pk_f32_fp8((int)p, false);
    hi = __builtin_amdgcn_cvt_pk_f32_fp8((int)p, true);
#else
    auto dec = [](unsigned byte) -> float {
        unsigned s = (byte & 0x80u) << 24;
        unsigned em = byte & 0x7fu;
        float nrm = __uint_as_float(s | ((em << 20) + 0x3C000000u));
        float sub = __uint_as_float(s | 0x3F800000u) * (float)em * 0.001953125f;
        return (em >= 8) ? nrm : sub;
    };
    lo = (f32x2){dec(p & 0xff), dec((p >> 8) & 0xff)};
    hi = (f32x2){dec((p >> 16) & 0xff), dec(p >> 24)};
#endif
}

__device__ __forceinline__ int perm256(int j) {
    return (j < 128) ? ((j >> 1) * 4 + (j & 1)) : (((j - 128) >> 1) * 4 + 2 + (j & 1));
}

// ---------------- weight prep: frag-major bf16 B tables ----------------
__global__ __launch_bounds__(256) void k_prepw(const float* __restrict__ ew, const float* __restrict__ bw,
                                               const float* __restrict__ lw,
                                               unsigned short* __restrict__ embB, unsigned short* __restrict__ bembB,
                                               unsigned short* __restrict__ waB, unsigned short* __restrict__ wcB) {
    int i = blockIdx.x * 256 + threadIdx.x;          // 0..81919
    if (i >= 81920) return;
    unsigned short* dst;
    int f, NKC, CT, mode;
    if (i < 12288)      { dst = embB;  f = i;         NKC = 3; CT = 2; mode = 0; }
    else if (i < 20480) { dst = bembB; f = i - 12288; NKC = 2; CT = 2; mode = 1; }
    else if (i < 53248) { dst = waB;   f = i - 20480; NKC = 4; CT = 4; mode = 2; }
    else                { dst = wcB;   f = i - 53248; NKC = 4; CT = 4; mode = 3; }
    int j = f & 7, l = (f >> 3) & 63;
    int r2 = f >> 9;
    int c = r2 % CT;
    int r3 = r2 / CT;
    int kc = r3 % NKC, w = r3 / NKC;
    int k = kc * 32 + ((l >> 4) & 3) * 8 + j;
    int n = (w * CT + c) * 16 + (l & 15);
    float v;
    if (mode == 0)      v = (k < 92) ? ew[k * 128 + n] : 0.f;
    else if (mode == 1) v = (k < 40) ? bw[k * 128 + n] : 0.f;
    else if (mode == 2) v = lw[k * 256 + n] + lw[(k + 256) * 256 + n];
    else                v = lw[(k + 128) * 256 + n];
    dst[f] = f2bf(v);
}

// ---------------- fused 2-stage MFMA GEMM ----------------
// OMODE2: 1 = bf16-packed A + bf16 h out; 2 = fp8-packed C out
template<int KIN, int NKC1, int OMODE2>
__global__ __launch_bounds__(256) void mfma_fused(
    const float* __restrict__ in, const unsigned short* __restrict__ B1, const float* __restrict__ bias1,
    const unsigned short* __restrict__ B2, const float* __restrict__ bias2,
    unsigned short* __restrict__ hout, void* __restrict__ out2, int M)
{
    const int r0 = blockIdx.x * 32;
    const int t = threadIdx.x;
    const int w = t >> 6;
    const int l = t & 63;
    const int m = l & 15, q = l >> 4;

    __shared__ __align__(16) unsigned short als[32 * NKC1 * 32];
    __shared__ __align__(16) unsigned short hls[32 * 136];

    const int KP = NKC1 * 32;
    for (int i = t; i < 32 * KP; i += 256) {
        int r = i / KP, k = i - r * KP;
        int gr = r0 + r;
        float v = (gr < M && k < KIN) ? in[(size_t)gr * KIN + k] : 0.f;
        int idx = (((r >> 4) * NKC1 + (k >> 5)) * 64 + ((k >> 3) & 3) * 16 + (r & 15)) * 8 + (k & 7);
        als[idx] = f2bf(v);
    }
    bf16x8 b1[NKC1][2];
    const bf16x8* B1f = (const bf16x8*)B1;
#pragma unroll
    for (int kc = 0; kc < NKC1; kc++)
#pragma unroll
        for (int c = 0; c < 2; c++)
            b1[kc][c] = B1f[((w * NKC1 + kc) * 2 + c) * 64 + l];
    __syncthreads();

    f32x4 acc1[2][2];
#pragma unroll
    for (int c = 0; c < 2; c++) { acc1[c][0] = (f32x4){0.f,0.f,0.f,0.f}; acc1[c][1] = (f32x4){0.f,0.f,0.f,0.f}; }
    const bf16x8* af = (const bf16x8*)als;
#pragma unroll
    for (int kc = 0; kc < NKC1; kc++) {
        bf16x8 a0 = af[kc * 64 + l];
        bf16x8 a1 = af[(NKC1 + kc) * 64 + l];
#pragma unroll
        for (int c = 0; c < 2; c++) {
            acc1[c][0] = __builtin_amdgcn_mfma_f32_16x16x32_bf16(a0, b1[kc][c], acc1[c][0], 0, 0, 0);
            acc1[c][1] = __builtin_amdgcn_mfma_f32_16x16x32_bf16(a1, b1[kc][c], acc1[c][1], 0, 0, 0);
        }
    }
#pragma unroll
    for (int c = 0; c < 2; c++) {
        int n1 = (w * 2 + c) * 16 + m;
        float bv = bias1[n1];
#pragma unroll
        for (int hh = 0; hh < 2; hh++) {
#pragma unroll
            for (int r = 0; r < 4; r++) {
                int row = hh * 16 + q * 4 + r;
                float val = acc1[c][hh][r] + bv;
                unsigned short bf = f2bf(val);
                hls[row * 136 + n1] = bf;
                if (OMODE2 == 1 && r0 + row < M) hout[(size_t)(r0 + row) * 128 + n1] = bf;
            }
        }
    }
    __syncthreads();

    bf16x8 b2[4][4];
    const bf16x8* B2f = (const bf16x8*)B2;
#pragma unroll
    for (int kc = 0; kc < 4; kc++)
#pragma unroll
        for (int c = 0; c < 4; c++)
            b2[kc][c] = B2f[((w * 4 + kc) * 4 + c) * 64 + l];

    f32x4 acc2[4][2];
#pragma unroll
    for (int c = 0; c < 4; c++) { acc2[c][0] = (f32x4){0.f,0.f,0.f,0.f}; acc2[c][1] = (f32x4){0.f,0.f,0.f,0.f}; }
#pragma unroll
    for (int kc = 0; kc < 4; kc++) {
        bf16x8 a0 = *(const bf16x8*)(hls + m * 136 + kc * 32 + q * 8);
        bf16x8 a1 = *(const bf16x8*)(hls + (m + 16) * 136 + kc * 32 + q * 8);
#pragma unroll
        for (int c = 0; c < 4; c++) {
            acc2[c][0] = __builtin_amdgcn_mfma_f32_16x16x32_bf16(a0, b2[kc][c], acc2[c][0], 0, 0, 0);
            acc2[c][1] = __builtin_amdgcn_mfma_f32_16x16x32_bf16(a1, b2[kc][c], acc2[c][1], 0, 0, 0);
        }
    }
#pragma unroll
    for (int c = 0; c < 4; c++) {
        int n = (w * 4 + c) * 16 + m;
        float bv = bias2 ? bias2[n] : 0.f;
        int pj = perm256(n);
#pragma unroll
        for (int hh = 0; hh < 2; hh++) {
#pragma unroll
            for (int r = 0; r < 4; r++) {
                int row = r0 + hh * 16 + q * 4 + r;
                if (row < M) {
                    float val = acc2[c][hh][r] + bv;
                    if (OMODE2 == 1) ((unsigned short*)out2)[(size_t)row * 256 + pj] = f2bf(val);
                    else             ((unsigned char*)out2)[(size_t)row * 256 + pj] = f2fp8(val);
                }
            }
        }
    }
}

// ---------------- histograms ----------------
__global__ __launch_bounds__(256) void k_hist2(const int* __restrict__ idx0, const int* __restrict__ batch,
                                               int* __restrict__ hist, int* __restrict__ gcount, int E, int N) {
    int i = blockIdx.x * 256 + threadIdx.x;
    if (i < E) atomicAdd(&hist[idx0[i]], 1);
    if (i < N) atomicAdd(&gcount[batch[i]], 1);
}

// ---------------- single-block scan ----------------
__global__ __launch_bounds__(1024) void k_scanall(const int* __restrict__ hist, int* __restrict__ rowptr,
                                                  const int* __restrict__ gcount, int* __restrict__ gptr, int N) {
    __shared__ int s[1024];
    const int t = threadIdx.x;
    const int PER = (N + 1023) >> 10;
    const int b0 = t * PER;
    const int b1 = min(b0 + PER, N);
    int sum = 0;
    for (int i = b0; i < b1; i++) sum += hist[i];
    s[t] = sum;
    __syncthreads();
    for (int ofs = 1; ofs < 1024; ofs <<= 1) {
        int v = (t >= ofs) ? s[t - ofs] : 0;
        __syncthreads();
        s[t] += v;
        __syncthreads();
    }
    int run = s[t] - sum;
    for (int i = b0; i < b1; i++) {
        run += hist[i];
        rowptr[i + 1] = run;
    }
    if (t == 0) rowptr[0] = 0;
    __syncthreads();
    int gv = (t < 128) ? gcount[t] : 0;
    s[t] = gv;
    __syncthreads();
    for (int ofs = 1; ofs < 128; ofs <<= 1) {
        int v = (t >= ofs && t < 128) ? s[t - ofs] : 0;
        __syncthreads();
        if (t < 128) s[t] += v;
        __syncthreads();
    }
    if (t < 128) gptr[t + 1] = s[t];
    if (t == 0) gptr[0] = 0;
}

// ---------------- merged scatter (sidx1 stores BYTE offsets = idx1*256) ----------------
__global__ __launch_bounds__(256) void k_scatter2(const int* __restrict__ idx0, const int* __restrict__ idx1,
                                                  const int* __restrict__ batch,
                                                  const int* __restrict__ rowptr, const int* __restrict__ gptr,
                                                  int* __restrict__ fill, int* __restrict__ gfill,
                                                  int* __restrict__ sidx1, int* __restrict__ gnodes, int E, int N) {
    int i = blockIdx.x * 256 + threadIdx.x;
    if (i < E) {
        int n = idx0[i];
        int pos = rowptr[n] + atomicAdd(&fill[n], 1);
        sidx1[pos] = idx1[i] << 8;                       // byte offset of the 256B fp8 row
    }
    if (i < N) {
        int g = batch[i];
        int pos = gptr[g] + atomicAdd(&gfill[g], 1);
        gnodes[pos] = i;
    }
}

// ---------------- deg-weighted A moments: sum(deg*a), sum(deg*a^2) ----------------
__global__ __launch_bounds__(256) void k_rowstats(const uint2* __restrict__ A16, const int* __restrict__ hist,
                                                  float* __restrict__ gsum, float* __restrict__ gsq, int N) {
    __shared__ float4 lsm4[256], lsq4[256];
    const int t = threadIdx.x;
    const int s = t >> 6, l = t & 63;
    const int w0 = blockIdx.x * 4 + s;
    const int nw = gridDim.x * 4;
    f32x2 smF = {0.f,0.f}, smC = {0.f,0.f}, sqF = {0.f,0.f}, sqC = {0.f,0.f};
    for (int n = w0; n < N; n += nw) {
        float dg = (float)hist[n];
        uint2 a8 = A16[(size_t)n * 64 + l];
        f32x2 aF = {bflo(a8.x), bfhi(a8.x)};
        f32x2 aC = {bflo(a8.y), bfhi(a8.y)};
        f32x2 dF = aF * dg;
        f32x2 dC = aC * dg;
        smF += dF; smC += dC;
        sqF = pk_fma2(dF, aF, sqF);
        sqC = pk_fma2(dC, aC, sqC);
    }
    lsm4[t] = (float4){smF.x, smF.y, smC.x, smC.y};
    lsq4[t] = (float4){sqF.x, sqF.y, sqC.x, sqC.y};
    __syncthreads();
    const float* fm = (const float*)lsm4;
    const float* fq = (const float*)lsq4;
    float vs = fm[t] + fm[256 + t] + fm[512 + t] + fm[768 + t];
    float vq = fq[t] + fq[256 + t] + fq[512 + t] + fq[768 + t];
    atomicAdd(&gsum[t], vs);
    atomicAdd(&gsq[t], vq);
}

// ---------------- BN1 edge stats: sum(c), sum(c^2) + 2*sum(a*csr) (cross term) ----------------
// Per-edge body: 2 decode + 2 pk_add + 2 pk_fma. Gathers are saddr-form
// (SGPR base + 32-bit voffset from pre-scaled sidx1).
__global__ __launch_bounds__(256) void k_stats(const uint2* __restrict__ A16, const unsigned char* __restrict__ Cp8b,
                                               const int* __restrict__ rowptr, const int* __restrict__ sidx1,
                                               float* __restrict__ gsum, float* __restrict__ gsq,
                                               int E, int N, int per_slot) {
    __shared__ float4 lsm4[256], lsq4[256];
    const int t = threadIdx.x;
    const int s = t >> 6, l = t & 63;
    const unsigned lo4 = (unsigned)(l << 2);
    const long base = (long)(blockIdx.x * 4 + s) * per_slot;
    const int e0 = (int)min((long)E, base);
    const int e1 = (int)min((long)E, base + per_slot);
    f32x2 smF = {0.f,0.f}, smC = {0.f,0.f};
    f32x2 sqF = {0.f,0.f}, sqC = {0.f,0.f};        // accumulates c^2 AND 2*a*csr
    f32x2 csrF = {0.f,0.f}, csrC = {0.f,0.f};
    f32x2 aF2 = {0.f,0.f}, aC2 = {0.f,0.f};        // 2*a of current node
    int cur_n = 0, bound = 0;

    auto flush = [&]() {
        smF += csrF; smC += csrC;
        sqF = pk_fma2(aF2, csrF, sqF);
        sqC = pk_fma2(aC2, csrC, sqC);
        csrF = (f32x2){0.f,0.f}; csrC = (f32x2){0.f,0.f};
    };
    auto loadA = [&](int n) {
        uint2 a8 = A16[(size_t)n * 64 + l];
        aF2 = (f32x2){bflo(a8.x) * 2.f, bfhi(a8.x) * 2.f};
        aC2 = (f32x2){bflo(a8.y) * 2.f, bfhi(a8.y) * 2.f};
    };

    if (e0 < e1) {
        // wave-uniform binary search: cur_n = max n with rowptr[n] <= e0
        int lo = 0, hi = N;
        while (lo + 1 < hi) {
            int mid = (lo + hi) >> 1;
            if (rowptr[mid] <= e0) lo = mid; else hi = mid;
        }
        cur_n = lo;
        bound = rowptr[cur_n + 1];
        loadA(cur_n);
    }

    auto proc = [&](int e, unsigned p) {
        if (e >= bound) {                            // wave-uniform
            flush();
            do { cur_n++; bound = rowptr[cur_n + 1]; } while (bound <= e);
            loadA(cur_n);
        }
        f32x2 vf, vc;
        fp8pair(p, vf, vc);
        csrF += vf; csrC += vc;
        sqF = pk_fma2(vf, vf, sqF);
        sqC = pk_fma2(vc, vc, sqC);
    };

    int e = e0;
    for (; e + 8 <= e1; e += 8) {
        int4 mm0 = *(const int4*)(sidx1 + e);
        int4 mm1 = *(const int4*)(sidx1 + e + 4);
        unsigned p0 = *(const unsigned*)(Cp8b + ((unsigned)mm0.x + lo4));
        unsigned p1 = *(const unsigned*)(Cp8b + ((unsigned)mm0.y + lo4));
        unsigned p2 = *(const unsigned*)(Cp8b + ((unsigned)mm0.z + lo4));
        unsigned p3 = *(const unsigned*)(Cp8b + ((unsigned)mm0.w + lo4));
        unsigned p4 = *(const unsigned*)(Cp8b + ((unsigned)mm1.x + lo4));
        unsigned p5 = *(const unsigned*)(Cp8b + ((unsigned)mm1.y + lo4));
        unsigned p6 = *(const unsigned*)(Cp8b + ((unsigned)mm1.z + lo4));
        unsigned p7 = *(const unsigned*)(Cp8b + ((unsigned)mm1.w + lo4));
        proc(e, p0); proc(e + 1, p1); proc(e + 2, p2); proc(e + 3, p3);
        proc(e + 4, p4); proc(e + 5, p5); proc(e + 6, p6); proc(e + 7, p7);
    }
    for (; e < e1; e++) proc(e, *(const unsigned*)(Cp8b + ((unsigned)sidx1[e] + lo4)));
    flush();

    lsm4[t] = (float4){smF.x, smF.y, smC.x, smC.y};
    lsq4[t] = (float4){sqF.x, sqF.y, sqC.x, sqC.y};
    __syncthreads();
    const float* fm = (const float*)lsm4;
    const float* fq = (const float*)lsq4;
    float vs = fm[t] + fm[256 + t] + fm[512 + t] + fm[768 + t];
    float vq = fq[t] + fq[256 + t] + fq[512 + t] + fq[768 + t];
    atomicAdd(&gsum[t], vs);
    atomicAdd(&gsq[t], vq);
}

// ---------------- fused BN1-finalize + msg + segment softmax (4 waves/block, 1 node/wave) ----------------
// Packed-f32 per-edge math; saddr gathers via pre-scaled sidx1.
__global__ __launch_bounds__(256) void k_aggr(const uint2* __restrict__ A16, const unsigned char* __restrict__ Cp8b,
                                              const int* __restrict__ rowptr, const int* __restrict__ sidx1,
                                              const float* __restrict__ bn1_sum, const float* __restrict__ bn1_sq,
                                              const float* __restrict__ g1, const float* __restrict__ b1,
                                              const float* __restrict__ tptr, unsigned* __restrict__ out,
                                              float invE, int N) {
    const int n = blockIdx.x * 4 + (threadIdx.x >> 6);
    if (n >= N) return;
    const int l = threadIdx.x & 63;
    const float t = tptr[0];
    const float4 sum4 = ((const float4*)bn1_sum)[l];
    const float4 sq4  = ((const float4*)bn1_sq)[l];
    const float2 gf = ((const float2*)g1)[l];
    const float2 gc = ((const float2*)(g1 + 128))[l];
    const float2 bf2 = ((const float2*)b1)[l];
    const float2 bc2 = ((const float2*)(b1 + 128))[l];
    auto mkss = [&](float sum, float sq, float gg, float bb, float& sc, float& sh) {
        float mu = sum * invE;
        float var = sq * invE - mu * mu;
        sc = gg * rsqrtf(var + EPS_BN);
        sh = fmaf(-mu, sc, bb);
    };
    float scx, shx, scy, shy, scz, shz, scw, shw;
    mkss(sum4.x, sq4.x, gf.x, bf2.x, scx, shx);
    mkss(sum4.y, sq4.y, gf.y, bf2.y, scy, shy);
    mkss(sum4.z, sq4.z, gc.x, bc2.x, scz, shz);
    mkss(sum4.w, sq4.w, gc.y, bc2.y, scw, shw);

    uint2 a8 = A16[(size_t)n * 64 + l];
    const float apx = bflo(a8.x), apy = bfhi(a8.x), apz = bflo(a8.y), apw = bfhi(a8.y);
    const f32x2 sF = {-scx * LOG2E, -scy * LOG2E};
    const f32x2 bF = {-fmaf(apx, scx, shx) * LOG2E, -fmaf(apy, scy, shy) * LOG2E};
    const f32x2 sC = {scz * LOG2E, scw * LOG2E};
    const f32x2 bC = {fmaf(apz, scz, shz) * LOG2E, fmaf(apw, scw, shw) * LOG2E};

    const int e0 = rowptr[n], e1 = rowptr[n + 1];
    const unsigned lo4 = (unsigned)(l << 2);
    f32x2 den = {0.f,0.f}, num = {0.f,0.f};

    auto proc = [&](unsigned p) {
        f32x2 vf, vc;
        fp8pair(p, vf, vc);
        f32x2 argf = pk_fma2(vf, sF, bF);            // -zf_hat * log2e
        f32x2 argc = pk_fma2(vc, sC, bC);            //  zc_hat * log2e
        f32x2 ef = {fexp2(argf.x), fexp2(argf.y)};
        f32x2 uu = {fexp2(argc.x), fexp2(argc.y)};
        f32x2 d1 = ef + 1.f;
        f32x2 u1 = uu + 1.f;
        f32x2 sig = {__builtin_amdgcn_rcpf(d1.x), __builtin_amdgcn_rcpf(d1.y)};
        f32x2 lg = {flog2(u1.x), flog2(u1.y)};
        f32x2 M = sig * lg;
        f32x2 tM = M * t;
        f32x2 w = {fexp2(tM.x), fexp2(tM.y)};
        den += w;
        num = pk_fma2(M, w, num);
    };

    if (e1 > e0) {
        unsigned cur[4];
        int cb = min(e1 - e0, 4);
#pragma unroll
        for (int i = 0; i < 4; i++)
            if (i < cb) cur[i] = *(const unsigned*)(Cp8b + ((unsigned)sidx1[e0 + i] + lo4));
        for (int eb = e0; eb < e1; eb += 4) {
            int nb = min(max(e1 - (eb + 4), 0), 4);
            unsigned nxt[4];
#pragma unroll
            for (int i = 0; i < 4; i++)
                if (i < nb) nxt[i] = *(const unsigned*)(Cp8b + ((unsigned)sidx1[eb + 4 + i] + lo4));
            int pb = min(e1 - eb, 4);
#pragma unroll
            for (int i = 0; i < 4; i++)
                if (i < pb) proc(cur[i]);
#pragma unroll
            for (int i = 0; i < 4; i++) cur[i] = nxt[i];
        }
    }
    float ox = (e1 > e0) ? LN2 * num.x / den.x : 0.f;
    float oy = (e1 > e0) ? LN2 * num.y / den.y : 0.f;
    out[(size_t)n * 64 + l] = pack2bf(ox, oy);       // channels 2l, 2l+1 as bf16
}

// ---------------- BN2 stats (bf16 outbuf) ----------------
__global__ __launch_bounds__(128) void k_bn2stats(const unsigned short* __restrict__ out, float* __restrict__ sum,
                                                  float* __restrict__ sq, int N) {
    const int c = threadIdx.x;
    const int n0 = blockIdx.x * 64;
    const int nend = min(n0 + 64, N);
    float sm = 0.f, s2 = 0.f;
    for (int n = n0; n < nend; n++) {
        float v = bfu16(out[(size_t)n * 128 + c]);
        sm += v;
        s2 = fmaf(v, v, s2);
    }
    atomicAdd(&sum[c], sm);
    atomicAdd(&sq[c], s2);
}

// ---------------- fused BN2-finalize + residual+softplus + mean-pool (bf16 inputs) ----------------
template<int SPLIT>
__global__ __launch_bounds__(128) void k_h2pool(const unsigned short* __restrict__ out,
                                                const unsigned short* __restrict__ h,
                                                const int* __restrict__ gptr, const int* __restrict__ gnodes,
                                                const float* __restrict__ bn2_sum, const float* __restrict__ bn2_sq,
                                                const float* __restrict__ g2, const float* __restrict__ b2,
                                                float* __restrict__ pooled, float invN) {
    const int g = blockIdx.x & 127;
    const int sp = blockIdx.x >> 7;
    const int c = threadIdx.x;
    float mu = bn2_sum[c] * invN;
    float var = bn2_sq[c] * invN - mu * mu;
    float sc = g2[c] * rsqrtf(var + EPS_BN);
    float sh = fmaf(-mu, sc, b2[c]);
    const int i0 = gptr[g], i1 = gptr[g + 1];
    float acc = 0.f;
    for (int i = i0 + sp; i < i1; i += SPLIT) {
        int n = gnodes[i];
        float v = fmaf(bfu16(out[(size_t)n * 128 + c]), sc, sh) + bfu16(h[(size_t)n * 128 + c]);
        acc += softplus_fast(v);
    }
    if (acc != 0.f) atomicAdd(&pooled[g * 128 + c], acc);
}

// ---------------- head ----------------
__global__ __launch_bounds__(256) void k_head(const float* __restrict__ pooled, const int* __restrict__ gcount,
                                              const float* __restrict__ l1w, const float* __restrict__ l1b,
                                              const float* __restrict__ outw, const float* __restrict__ outb,
                                              float* __restrict__ dout) {
    __shared__ float p[128];
    __shared__ float red[256];
    const int g = blockIdx.x;
    const int j = threadIdx.x;
    if (j < 128) {
        float cnt = (float)max(gcount[g], 1);
        p[j] = pooled[g * 128 + j] / cnt;
    }
    __syncthreads();
    float acc = l1b[j];
    for (int k = 0; k < 128; k++) acc = fmaf(p[k], l1w[k * 256 + j], acc);
    red[j] = softplus_fast(acc) * outw[j];
    __syncthreads();
    for (int s = 128; s > 0; s >>= 1) {
        if (j < s) red[j] += red[j + s];
        __syncthreads();
    }
    if (j == 0) dout[g] = red[0] + outb[0];
}

// ---------------- launch ----------------
extern "C" void kernel_launch(void* const* d_in, const int* in_sizes, int n_in,
                              void* d_out, int out_size, void* d_ws, size_t ws_size,
                              hipStream_t stream) {
    const float* x        = (const float*)d_in[0];
    const float* hedge    = (const float*)d_in[1];
    const int*   iri      = (const int*)d_in[2];
    const int*   batch    = (const int*)d_in[3];
    const float* embed_w  = (const float*)d_in[5];
    const float* embed_b  = (const float*)d_in[6];
    const float* bembed_w = (const float*)d_in[7];
    const float* bembed_b = (const float*)d_in[8];
    const float* lin_w    = (const float*)d_in[9];
    const float* lin_b    = (const float*)d_in[10];
    const float* bn1_g    = (const float*)d_in[11];
    const float* bn1_b    = (const float*)d_in[12];
    const float* bn2_g    = (const float*)d_in[13];
    const float* bn2_b    = (const float*)d_in[14];
    const float* aggr_t   = (const float*)d_in[15];
    const float* l1_w     = (const float*)d_in[16];
    const float* l1_b     = (const float*)d_in[17];
    const float* out_w    = (const float*)d_in[18];
    const float* out_b    = (const float*)d_in[19];

    const int N   = in_sizes[0] / 92;
    const int NHE = in_sizes[1] / 40;
    const int E   = in_sizes[2] / 3;
    const int* idx0 = iri;
    const int* idx1 = iri + E;

    float* ws = (float*)d_ws;
    size_t off = 0;
    auto alloc = [&](size_t elems) -> float* {
        float* p = ws + off;
        off += (elems + 63) & ~(size_t)63;
        return p;
    };
    unsigned short* h16 = (unsigned short*)alloc((size_t)N * 64);   // N*128 bf16
    uint2* A16    = (uint2*)alloc((size_t)N * 128);                 // N*256 bf16 packed
    unsigned* Cp8 = (unsigned*)alloc((size_t)NHE * 64);             // NHE*256 fp8 packed
    unsigned short* embB  = (unsigned short*)alloc(6144);
    unsigned short* bembB = (unsigned short*)alloc(4096);
    unsigned short* waB   = (unsigned short*)alloc(16384);
    unsigned short* wcB   = (unsigned short*)alloc(16384);
    int*   rowptr = (int*)alloc((size_t)N + 1);
    int*   sidx1  = (int*)alloc((size_t)E + 8);
    int*   gptr   = (int*)alloc(129);
    int*   gnodes = (int*)alloc((size_t)N);
    unsigned* outbuf = (unsigned*)alloc((size_t)N * 64);            // N*128 bf16
    // contiguous zero region
    float* zbase  = ws + off;
    int*   hist   = (int*)alloc((size_t)N);
    int*   fill   = (int*)alloc((size_t)N);
    int*   gfill  = (int*)alloc(128);
    float* bn1_sum = alloc(256);
    float* bn1_sq  = alloc(256);
    float* bn2_sum = alloc(128);
    float* bn2_sq  = alloc(128);
    float* pooled  = alloc(128 * 128);
    int*   gcount  = (int*)alloc(128);
    size_t zbytes = (size_t)((ws + off) - zbase) * sizeof(float);
    (void)ws_size;  // ~77MB; fit verified

    hipMemsetAsync(zbase, 0, zbytes, stream);

    // frag-major bf16 weight prep + fused MFMA GEMM chains
    k_prepw<<<320, 256, 0, stream>>>(embed_w, bembed_w, lin_w, embB, bembB, waB, wcB);
    const int mtN   = (N + 31) / 32;
    const int mtNHE = (NHE + 31) / 32;
    mfma_fused<92, 3, 1><<<mtN, 256, 0, stream>>>(x, embB, embed_b, waB, lin_b, h16, A16, N);
    mfma_fused<40, 2, 2><<<mtNHE, 256, 0, stream>>>(hedge, bembB, bembed_b, wcB, nullptr, nullptr, Cp8, NHE);

    // CSR build
    k_hist2<<<(E + 255) / 256, 256, 0, stream>>>(idx0, batch, hist, gcount, E, N);
    k_scanall<<<1, 1024, 0, stream>>>(hist, rowptr, gcount, gptr, N);
    k_scatter2<<<(E + 255) / 256, 256, 0, stream>>>(idx0, idx1, batch, rowptr, gptr,
                                                    fill, gfill, sidx1, gnodes, E, N);

    // BN1 stats: deg-weighted A moments (N-row stream) + edge pass (C moments + cross)
    k_rowstats<<<256, 256, 0, stream>>>(A16, hist, bn1_sum, bn1_sq, N);
    const int STATS_BLOCKS = 2048;
    int per_slot = ((E + STATS_BLOCKS * 4 - 1) / (STATS_BLOCKS * 4) + 7) & ~7;
    k_stats<<<STATS_BLOCKS, 256, 0, stream>>>(A16, (const unsigned char*)Cp8, rowptr, sidx1,
                                              bn1_sum, bn1_sq, E, N, per_slot);

    // fused BN1-finalize + message + softmax aggregation
    k_aggr<<<(N + 3) / 4, 256, 0, stream>>>(A16, (const unsigned char*)Cp8, rowptr, sidx1,
                                            bn1_sum, bn1_sq, bn1_g, bn1_b, aggr_t, outbuf,
                                            1.0f / (float)E, N);

    // BN2 stats + fused finalize/residual/softplus/pool
    k_bn2stats<<<(N + 63) / 64, 128, 0, stream>>>((const unsigned short*)outbuf, bn2_sum, bn2_sq, N);
    k_h2pool<16><<<128 * 16, 128, 0, stream>>>((const unsigned short*)outbuf, h16, gptr, gnodes,
                                               bn2_sum, bn2_sq, bn2_g, bn2_b, pooled, 1.0f / (float)N);

    // head
    k_head<<<128, 256, 0, stream>>>(pooled, gcount, l1_w, l1_b, out_w, out_b, (float*)d_out);
}